// Round 1
// baseline (2026.884 us; speedup 1.0000x reference)
//
#include <hip/hip_runtime.h>
#include <cstdint>
#include <cstddef>

#define BN 16384   // b*n rows
#define C  512     // feature dim
#define M  8192    // codebook size

#define MT 64      // row tile
#define NT 128     // code tile
#define KT 32      // k tile
#define NSPLIT 2   // codes split across blockIdx.y

// ---------------- kernel 1: ||k||^2 per codebook row ----------------
__global__ void knorm_k(const float* __restrict__ emb, float* __restrict__ knorm) {
    int gw   = (blockIdx.x * blockDim.x + threadIdx.x) >> 6;
    int lane = threadIdx.x & 63;
    int nw   = (gridDim.x * blockDim.x) >> 6;
    for (int row = gw; row < M; row += nw) {
        const float4* p = (const float4*)(emb + (size_t)row * C);
        float s = 0.f;
#pragma unroll
        for (int j = 0; j < 2; ++j) {
            float4 v = p[lane + 64 * j];
            s += v.x * v.x + v.y * v.y + v.z * v.z + v.w * v.w;
        }
#pragma unroll
        for (int o = 32; o > 0; o >>= 1) s += __shfl_down(s, o, 64);
        if (lane == 0) knorm[row] = s;
    }
}

// ---------------- kernel 2: distance GEMM + running argmin ----------------
// grid (BN/MT, NSPLIT), block 256.
// d(row,col) = knorm[col] - 2*dot(x[row], emb[col])   (||q||^2 dropped: row-const)
__global__ __launch_bounds__(256, 2) void argmin_k(
    const float* __restrict__ x, const float* __restrict__ emb,
    const float* __restrict__ knorm,
    float* __restrict__ pmin, int* __restrict__ pidx) {
    __shared__ float A_lds[KT][MT + 4];   // [k][row], pad 4 keeps float4 align
    __shared__ float B_lds[KT][NT + 4];   // [k][col]

    const int tid = threadIdx.x;
    const int tx = tid & 15;      // 16 col-groups (8 cols each)
    const int ty = tid >> 4;      // 16 row-groups (4 rows each)
    const int rowBase  = blockIdx.x * MT;
    const int colBase0 = blockIdx.y * (M / NSPLIT);

    const int kq = (tid & 7) * 4; // k quad for staging
    const int sr = tid >> 3;      // 0..31 staging row/col

    float rval[4];
    int   ridx[4];
#pragma unroll
    for (int i = 0; i < 4; ++i) { rval[i] = 3.4e38f; ridx[i] = 0; }

    for (int nt = 0; nt < (M / NSPLIT) / NT; ++nt) {
        const int colBase = colBase0 + nt * NT;
        float acc[4][8];
#pragma unroll
        for (int i = 0; i < 4; ++i)
#pragma unroll
            for (int j = 0; j < 8; ++j) acc[i][j] = 0.f;

        for (int kt = 0; kt < C / KT; ++kt) {
            const int k0 = kt * KT;
            __syncthreads();
            // stage A: 64 rows x 32 k, transposed into [k][row]
#pragma unroll
            for (int b = 0; b < 2; ++b) {
                int row = sr + 32 * b;
                float4 v = *(const float4*)(x + (size_t)(rowBase + row) * C + k0 + kq);
                A_lds[kq + 0][row] = v.x; A_lds[kq + 1][row] = v.y;
                A_lds[kq + 2][row] = v.z; A_lds[kq + 3][row] = v.w;
            }
            // stage B: 128 cols x 32 k
#pragma unroll
            for (int b = 0; b < 4; ++b) {
                int col = sr + 32 * b;
                float4 v = *(const float4*)(emb + (size_t)(colBase + col) * C + k0 + kq);
                B_lds[kq + 0][col] = v.x; B_lds[kq + 1][col] = v.y;
                B_lds[kq + 2][col] = v.z; B_lds[kq + 3][col] = v.w;
            }
            __syncthreads();
#pragma unroll
            for (int k = 0; k < KT; ++k) {
                float4 a  = *(const float4*)&A_lds[k][ty * 4];
                float4 b0 = *(const float4*)&B_lds[k][tx * 8];
                float4 b1 = *(const float4*)&B_lds[k][tx * 8 + 4];
                float av[4] = { a.x, a.y, a.z, a.w };
                float bv[8] = { b0.x, b0.y, b0.z, b0.w, b1.x, b1.y, b1.z, b1.w };
#pragma unroll
                for (int i = 0; i < 4; ++i)
#pragma unroll
                    for (int j = 0; j < 8; ++j)
                        acc[i][j] = fmaf(av[i], bv[j], acc[i][j]);
            }
        }
        // epilogue for this N-tile: distances + running min
#pragma unroll
        for (int j = 0; j < 8; ++j) {
            int col = colBase + tx * 8 + j;
            float kn = knorm[col];
#pragma unroll
            for (int i = 0; i < 4; ++i) {
                float d = fmaf(-2.0f, acc[i][j], kn);
                if (d < rval[i] || (d == rval[i] && col < ridx[i])) {
                    rval[i] = d; ridx[i] = col;
                }
            }
        }
    }

    // cross-thread reduce over tx (16 consecutive lanes share rows)
#pragma unroll
    for (int i = 0; i < 4; ++i) {
#pragma unroll
        for (int m = 1; m < 16; m <<= 1) {
            float ov = __shfl_xor(rval[i], m, 64);
            int   oi = __shfl_xor(ridx[i], m, 64);
            if (ov < rval[i] || (ov == rval[i] && oi < ridx[i])) {
                rval[i] = ov; ridx[i] = oi;
            }
        }
        if (tx == 0) {
            int row = rowBase + ty * 4 + i;
            pmin[(size_t)blockIdx.y * BN + row] = rval[i];
            pidx[(size_t)blockIdx.y * BN + row] = ridx[i];
        }
    }
}

// ---------------- kernel 3: merge splits -> float indices ----------------
__global__ void merge_k(const float* __restrict__ pmin, const int* __restrict__ pidx,
                        float* __restrict__ out_idx) {
    int row = blockIdx.x * blockDim.x + threadIdx.x;
    if (row >= BN) return;
    float v0 = pmin[row], v1 = pmin[BN + row];
    int   i0 = pidx[row], i1 = pidx[BN + row];
    int bi = (v1 < v0) ? i1 : i0;  // tie -> split 0 (lower index)
    out_idx[row] = (float)bi;
}

// ---------------- kernel 4: gather z_st + scatter onehot ones ----------------
__global__ void gather_k(const float* __restrict__ emb, const float* __restrict__ out_idx,
                         float* __restrict__ zst, float* __restrict__ onehot) {
    int row = blockIdx.x;
    int idx = (int)out_idx[row];
    const float4* src = (const float4*)(emb + (size_t)idx * C);
    float4* dst = (float4*)(zst + (size_t)row * C);
    dst[threadIdx.x] = src[threadIdx.x];
    if (threadIdx.x == 0) onehot[(size_t)row * M + idx] = 1.0f;
}

// ---------------- kernel 5: perplexity via LDS histogram ----------------
__global__ void perp_k(const float* __restrict__ out_idx, float* __restrict__ out_perp) {
    __shared__ int hist[M];
    __shared__ float red[256];
    int tid = threadIdx.x;
    for (int j = tid; j < M; j += 256) hist[j] = 0;
    __syncthreads();
    for (int j = tid; j < BN; j += 256) atomicAdd(&hist[(int)out_idx[j]], 1);
    __syncthreads();
    float s = 0.f;
    for (int j = tid; j < M; j += 256) {
        float p = (float)hist[j] * (1.0f / (float)BN);
        s += p * logf(p + 1e-10f);
    }
    red[tid] = s; __syncthreads();
    for (int o = 128; o > 0; o >>= 1) {
        if (tid < o) red[tid] += red[tid + o];
        __syncthreads();
    }
    if (tid == 0) out_perp[0] = expf(-red[0]);
}

extern "C" void kernel_launch(void* const* d_in, const int* in_sizes, int n_in,
                              void* d_out, int out_size, void* d_ws, size_t ws_size,
                              hipStream_t stream) {
    const float* x   = (const float*)d_in[0];
    const float* emb = (const float*)d_in[1];

    float* out        = (float*)d_out;
    float* out_zst    = out;                                   // 8388608
    float* out_idx    = out + (size_t)BN * C;                  // 16384
    float* out_onehot = out_idx + BN;                          // 134217728
    float* out_perp   = out_onehot + (size_t)BN * M;           // 1

    // ws layout (floats): knorm[M], pmin[2*BN], pidx[2*BN]  => ~295 KB
    float* knorm = (float*)d_ws;
    float* pmin  = knorm + M;
    int*   pidx  = (int*)(pmin + (size_t)NSPLIT * BN);

    hipMemsetAsync(out_onehot, 0, (size_t)BN * M * sizeof(float), stream);

    knorm_k<<<64, 256, 0, stream>>>(emb, knorm);
    argmin_k<<<dim3(BN / MT, NSPLIT), 256, 0, stream>>>(x, emb, knorm, pmin, pidx);
    merge_k<<<BN / 256, 256, 0, stream>>>(pmin, pidx, out_idx);
    gather_k<<<BN, 128, 0, stream>>>(emb, out_idx, out_zst, out_onehot);
    perp_k<<<1, 256, 0, stream>>>(out_idx, out_perp);
}

// Round 3
// 1142.145 us; speedup vs baseline: 1.7746x; 1.7746x over previous
//
#include <hip/hip_runtime.h>
#include <cstdint>
#include <cstddef>

#define BNR 16384   // b*n rows
#define C   512     // feature dim
#define M   8192    // codebook size
#define K3  1536    // 3x expanded K (hi,hi,lo) x (hi,lo,hi)
#define NSPLIT 8
#define NTILES 8    // 128-col tiles per split

typedef float f32x4 __attribute__((ext_vector_type(4)));
typedef short s16x8 __attribute__((ext_vector_type(8)));
typedef unsigned short u16;

static __device__ __forceinline__ u16 f2bf(float f) {
    unsigned u = __float_as_uint(f);
    unsigned r = (u + 0x7FFFu + ((u >> 16) & 1u)) >> 16;
    return (u16)r;
}
static __device__ __forceinline__ float bf2f(u16 b) {
    return __uint_as_float(((unsigned)b) << 16);
}
static __device__ __forceinline__ void gl_lds16(const void* g, void* l) {
    __builtin_amdgcn_global_load_lds(
        (const __attribute__((address_space(1))) void*)g,
        (__attribute__((address_space(3))) void*)l, 16, 0, 0);
}

// ---------------- ||k||^2 per codebook row (exact fp32) ----------------
__global__ void knorm_k(const float* __restrict__ emb, float* __restrict__ knorm) {
    int gw   = (blockIdx.x * blockDim.x + threadIdx.x) >> 6;
    int lane = threadIdx.x & 63;
    int nw   = (gridDim.x * blockDim.x) >> 6;
    for (int row = gw; row < M; row += nw) {
        const float4* p = (const float4*)(emb + (size_t)row * C);
        float s = 0.f;
#pragma unroll
        for (int j = 0; j < 2; ++j) {
            float4 v = p[lane + 64 * j];
            s += v.x * v.x + v.y * v.y + v.z * v.z + v.w * v.w;
        }
#pragma unroll
        for (int o = 32; o > 0; o >>= 1) s += __shfl_down(s, o, 64);
        if (lane == 0) knorm[row] = s;
    }
}

// ---------------- fp32 -> split-bf16 triples ----------------
// x side: {hi, hi, lo}
__global__ void cvt_x_k(const float* __restrict__ in, u16* __restrict__ outp) {
    int t = blockIdx.x * 256 + threadIdx.x;     // one float4 per thread
    int row = t >> 7;                           // 128 float4 per row
    int c4  = t & 127;
    float4 v = *(const float4*)(in + ((size_t)row << 9) + c4 * 4);
    float e[4] = { v.x, v.y, v.z, v.w };
    u16 o[12];
#pragma unroll
    for (int j = 0; j < 4; ++j) {
        u16 h = f2bf(e[j]);
        u16 l = f2bf(e[j] - bf2f(h));
        o[3 * j + 0] = h; o[3 * j + 1] = h; o[3 * j + 2] = l;
    }
    u16* dst = outp + (size_t)row * K3 + c4 * 12;
#pragma unroll
    for (int j = 0; j < 3; ++j) *(ushort4*)(dst + 4 * j) = *(ushort4*)(o + 4 * j);
}
// emb side: {hi, lo, hi}
__global__ void cvt_e_k(const float* __restrict__ in, u16* __restrict__ outp) {
    int t = blockIdx.x * 256 + threadIdx.x;
    int row = t >> 7;
    int c4  = t & 127;
    float4 v = *(const float4*)(in + ((size_t)row << 9) + c4 * 4);
    float e[4] = { v.x, v.y, v.z, v.w };
    u16 o[12];
#pragma unroll
    for (int j = 0; j < 4; ++j) {
        u16 h = f2bf(e[j]);
        u16 l = f2bf(e[j] - bf2f(h));
        o[3 * j + 0] = h; o[3 * j + 1] = l; o[3 * j + 2] = h;
    }
    u16* dst = outp + (size_t)row * K3 + c4 * 12;
#pragma unroll
    for (int j = 0; j < 3; ++j) *(ushort4*)(dst + 4 * j) = *(ushort4*)(o + 4 * j);
}

// ---------------- MFMA distance GEMM + running argmin ----------------
// grid (128, NSPLIT), block 256 = 4 waves.
// Wave w owns rows [w*32, w*32+32) x ALL 128 cols of the tile -> each row's
// candidate reduction sees the full split; pi1/pi2[row] has ONE writer.
// LDS layout: [kblock(8)][row(128)][8 elems] -> conflict-free ds_read_b128
__global__ __launch_bounds__(256, 2) void mfma_argmin_k(
    const short* __restrict__ x3, const short* __restrict__ e3,
    const float* __restrict__ knorm,
    int* __restrict__ pi1, int* __restrict__ pi2) {
    __shared__ __align__(16) short Abuf[8192];  // 16KB
    __shared__ __align__(16) short Bbuf[8192];  // 16KB

    const int tid  = threadIdx.x;
    const int lane = tid & 63;
    const int w    = tid >> 6;            // wave id 0..3
    const int g    = lane >> 4, r = lane & 15;
    const int rowBase  = blockIdx.x * 128;
    const int split    = blockIdx.y;
    const int colBase0 = split * (M / NSPLIT);

    float rv[8]; int ri[8];
#pragma unroll
    for (int s = 0; s < 8; ++s) { rv[s] = 3.0e38f; ri[s] = 0; }

    for (int nt = 0; nt < NTILES; ++nt) {
        const int colBase = colBase0 + nt * 128;
        f32x4 acc[2][8];
#pragma unroll
        for (int m = 0; m < 2; ++m)
#pragma unroll
            for (int n = 0; n < 8; ++n) acc[m][n] = (f32x4)(0.0f);

#pragma unroll 1
        for (int kt = 0; kt < K3 / 64; ++kt) {
            const int k0 = kt * 64;
            __syncthreads();
#pragma unroll
            for (int it = 0; it < 4; ++it) {
                int u = it * 256 + tid;
                int urow = u & 127, ukb = u >> 7;
                const short* as = x3 + (size_t)(rowBase + urow) * K3 + k0 + ukb * 8;
                const short* bs = e3 + (size_t)(colBase + urow) * K3 + k0 + ukb * 8;
                gl_lds16(as, &Abuf[u * 8]);
                gl_lds16(bs, &Bbuf[u * 8]);
            }
            __syncthreads();
#pragma unroll
            for (int ks = 0; ks < 2; ++ks) {
                s16x8 af[2], bfv[8];
#pragma unroll
                for (int m = 0; m < 2; ++m)
                    af[m] = *(const s16x8*)&Abuf[(((ks * 4 + g) * 128) + w * 32 + m * 16 + r) * 8];
#pragma unroll
                for (int n = 0; n < 8; ++n)
                    bfv[n] = *(const s16x8*)&Bbuf[(((ks * 4 + g) * 128) + n * 16 + r) * 8];
#pragma unroll
                for (int m = 0; m < 2; ++m)
#pragma unroll
                    for (int n = 0; n < 8; ++n)
                        acc[m][n] = __builtin_amdgcn_mfma_f32_16x16x32_bf16(
                            af[m], bfv[n], acc[m][n], 0, 0, 0);
            }
        }
        // epilogue: distances + running per-slot argmin (slot = (m,q))
#pragma unroll
        for (int n = 0; n < 8; ++n) {
            int col = colBase + n * 16 + r;
            float kn = knorm[col];
#pragma unroll
            for (int m = 0; m < 2; ++m)
#pragma unroll
                for (int q = 0; q < 4; ++q) {
                    float d = fmaf(-2.0f, acc[m][n][q], kn);
                    int s = m * 4 + q;
                    if (d < rv[s]) { rv[s] = d; ri[s] = col; }
                }
        }
    }

    // cross-lane top-2 merge within 16-lane groups (lex order on (v, idx))
#pragma unroll
    for (int s = 0; s < 8; ++s) {
        float v1 = rv[s]; int i1 = ri[s];
        float v2 = 3.0e38f; int i2 = 0x7fffffff;
#pragma unroll
        for (int msk = 1; msk < 16; msk <<= 1) {
            float ov1 = __shfl_xor(v1, msk, 64);
            int   oi1 = __shfl_xor(i1, msk, 64);
            float ov2 = __shfl_xor(v2, msk, 64);
            int   oi2 = __shfl_xor(i2, msk, 64);
            bool ob = (ov1 < v1) || (ov1 == v1 && oi1 < i1);
            float nbv = ob ? ov1 : v1;  int nbi = ob ? oi1 : i1;
            float c1v = ob ? ov2 : v2;  int c1i = ob ? oi2 : i2;  // winner's own 2nd
            float c2v = ob ? v1 : ov1;  int c2i = ob ? i1 : oi1;  // loser's 1st
            bool cb = (c2v < c1v) || (c2v == c1v && c2i < c1i);
            v1 = nbv; i1 = nbi;
            v2 = cb ? c2v : c1v; i2 = cb ? c2i : c1i;
        }
        if (r == 0) {
            int row = rowBase + w * 32 + (s >> 2) * 16 + g * 4 + (s & 3);
            pi1[(size_t)split * BNR + row] = i1;
            pi2[(size_t)split * BNR + row] = i2;
        }
    }
}

// ---------------- exact fp64 refine over 16 candidates/row ----------------
// block 256 = 4 waves = 4 rows; lane: cand c = lane&15, part p = lane>>4
__global__ void refine_k(const float* __restrict__ x, const float* __restrict__ emb,
                         const int* __restrict__ pi1, const int* __restrict__ pi2,
                         float* __restrict__ out_idx) {
    int row  = blockIdx.x * 4 + (threadIdx.x >> 6);
    int lane = threadIdx.x & 63;
    int c = lane & 15, p = lane >> 4;
    int cand = (c < 8) ? pi1[(size_t)c * BNR + row]
                       : pi2[(size_t)(c - 8) * BNR + row];
    const float4* qp = (const float4*)(x + (size_t)row * C);
    const float4* kp = (const float4*)(emb + (size_t)cand * C);
    double s = 0.0;
#pragma unroll 4
    for (int jj = 0; jj < 32; ++jj) {
        int j = p * 32 + jj;
        float4 q4 = qp[j], k4 = kp[j];
        double d0 = (double)q4.x - (double)k4.x;
        double d1 = (double)q4.y - (double)k4.y;
        double d2 = (double)q4.z - (double)k4.z;
        double d3 = (double)q4.w - (double)k4.w;
        s += d0 * d0 + d1 * d1 + d2 * d2 + d3 * d3;
    }
    s += __shfl_xor(s, 16, 64);
    s += __shfl_xor(s, 32, 64);
    double v = s; int bi = cand;
#pragma unroll
    for (int msk = 1; msk < 16; msk <<= 1) {
        double ov = __shfl_xor(v, msk, 64);
        int    oi = __shfl_xor(bi, msk, 64);
        if (ov < v || (ov == v && oi < bi)) { v = ov; bi = oi; }
    }
    if (lane == 0) out_idx[row] = (float)bi;
}

// ---------------- gather z_st + scatter onehot ones ----------------
__global__ void gather_k(const float* __restrict__ emb, const float* __restrict__ out_idx,
                         float* __restrict__ zst, float* __restrict__ onehot) {
    int row = blockIdx.x;
    int idx = (int)out_idx[row];
    const float4* src = (const float4*)(emb + (size_t)idx * C);
    float4* dst = (float4*)(zst + (size_t)row * C);
    dst[threadIdx.x] = src[threadIdx.x];
    if (threadIdx.x == 0) onehot[(size_t)row * M + idx] = 1.0f;
}

// ---------------- perplexity via LDS histogram ----------------
__global__ void perp_k(const float* __restrict__ out_idx, float* __restrict__ out_perp) {
    __shared__ int hist[M];
    __shared__ float red[256];
    int tid = threadIdx.x;
    for (int j = tid; j < M; j += 256) hist[j] = 0;
    __syncthreads();
    for (int j = tid; j < BNR; j += 256) atomicAdd(&hist[(int)out_idx[j]], 1);
    __syncthreads();
    float s = 0.f;
    for (int j = tid; j < M; j += 256) {
        float pb = (float)hist[j] * (1.0f / (float)BNR);
        s += pb * logf(pb + 1e-10f);
    }
    red[tid] = s; __syncthreads();
    for (int o = 128; o > 0; o >>= 1) {
        if (tid < o) red[tid] += red[tid + o];
        __syncthreads();
    }
    if (tid == 0) out_perp[0] = expf(-red[0]);
}

extern "C" void kernel_launch(void* const* d_in, const int* in_sizes, int n_in,
                              void* d_out, int out_size, void* d_ws, size_t ws_size,
                              hipStream_t stream) {
    const float* x   = (const float*)d_in[0];
    const float* emb = (const float*)d_in[1];

    float* out        = (float*)d_out;
    float* out_zst    = out;                              // 8388608
    float* out_idx    = out + (size_t)BNR * C;            // 16384
    float* out_onehot = out_idx + BNR;                    // 134217728
    float* out_perp   = out_onehot + (size_t)BNR * M;     // 1

    // scratch lives in the onehot region (memset afterwards)
    u16*   x3    = (u16*)out_onehot;                      // 48 MiB
    u16*   e3    = x3 + (size_t)BNR * K3;                 // 24 MiB
    float* knorm = (float*)(e3 + (size_t)M * K3);
    int*   pi1   = (int*)(knorm + M);
    int*   pi2   = pi1 + (size_t)NSPLIT * BNR;

    cvt_x_k<<<(BNR * C / 4) / 256, 256, 0, stream>>>(x, x3);
    cvt_e_k<<<(M * C / 4) / 256, 256, 0, stream>>>(emb, e3);
    knorm_k<<<64, 256, 0, stream>>>(emb, knorm);
    mfma_argmin_k<<<dim3(BNR / 128, NSPLIT), 256, 0, stream>>>(
        (const short*)x3, (const short*)e3, knorm, pi1, pi2);
    refine_k<<<BNR / 4, 256, 0, stream>>>(x, emb, pi1, pi2, out_idx);

    hipMemsetAsync(out_onehot, 0, (size_t)BNR * M * sizeof(float), stream);
    gather_k<<<BNR, 128, 0, stream>>>(emb, out_idx, out_zst, out_onehot);
    perp_k<<<1, 256, 0, stream>>>(out_idx, out_perp);
}